// Round 10
// baseline (123.649 us; speedup 1.0000x reference)
//
#include <hip/hip_runtime.h>
#include <cstdint>
#include <cstddef>

// ---- problem constants ----
constexpr int B_    = 8;
constexpr int HKV_  = 8;
constexpr int G_    = 2;      // query heads per kv head
constexpr int D_    = 128;
constexpr int HID_  = 2048;
constexpr int VOCAB_= 32000;
constexpr int BS_   = 16;
constexpr int MAXB_ = 256;
constexpr int L_    = 4096;

// ---- tiling ----
constexpr int KSP_QKV = 32;  constexpr int CK_QKV = HID_ / KSP_QKV;  // 64
constexpr int KSP_O   = 32;                                          // (unused name-keep)
constexpr int KSP_LM  = 16;  constexpr int CK_LM  = HID_ / KSP_LM;   // 128
constexpr int ACH     = 32;  constexpr int NACH   = L_ / ACH;        // 128 chunks of 32 tokens
constexpr int NCOL_QKV = HID_ + 1024 + 1024;                         // 4096

// ---- workspace layout (floats) ----
constexpr size_t OFF_PQKV = 0;                                         // 32*8*4096
constexpr size_t OFF_QB   = OFF_PQKV + (size_t)KSP_QKV*B_*NCOL_QKV;    // 8*2048 (scaled q)
constexpr size_t OFF_KNV  = OFF_QB   + (size_t)B_*HID_;                // 8*8*256 (kn|vn)
constexpr size_t OFF_PM   = OFF_KNV  + (size_t)B_*HKV_*2*D_;
constexpr size_t OFF_PL   = OFF_PM   + (size_t)B_*HKV_*NACH*G_;
constexpr size_t OFF_PACC = OFF_PL   + (size_t)B_*HKV_*NACH*G_;
constexpr size_t OFF_PO   = OFF_PACC + (size_t)B_*HKV_*NACH*G_*D_;     // 2M floats
constexpr size_t OFF_PLM  = OFF_PO   + (size_t)32*B_*HID_;
// end = OFF_PLM + 16*8*32000 ~= 7.9M floats ~= 32 MB

// ---- nontemporal load helpers ----
// NT on streamed operands (KV cache, Wq/Wk/Wv/Wo) so they don't evict Wlm from
// the 256 MB L3; Wlm uses cached loads (L3-persist across replays — round-6 win).
typedef float f32x4_t __attribute__((ext_vector_type(4)));
__device__ __forceinline__ float4 ntload4(const float* p) {
    f32x4_t v = __builtin_nontemporal_load((const f32x4_t*)p);
    return make_float4(v.x, v.y, v.z, v.w);
}
__device__ __forceinline__ float ntload1(const float* p) {
    return __builtin_nontemporal_load(p);
}

// ---------------- K1: fused q/k/v projection partials ----------------
__global__ __launch_bounds__(256) void k_qkv_part(const int* __restrict__ tokens,
        const float* __restrict__ embed,
        const float* __restrict__ Wq, const float* __restrict__ Wk,
        const float* __restrict__ Wv, float* __restrict__ pout) {
    __shared__ float xs[CK_QKV * 8];           // [kk][b]
    const int c  = blockIdx.y;
    const int k0 = c * CK_QKV;
    const int n  = blockIdx.x * 256 + threadIdx.x;   // 0..4095
    for (int idx = threadIdx.x; idx < CK_QKV*8; idx += 256) {
        int b = idx >> 6, kk = idx & (CK_QKV-1);
        xs[kk*8 + b] = embed[(size_t)tokens[b]*HID_ + k0 + kk];
    }
    const float* Wp; int stride, col;
    if (n < HID_)            { Wp = Wq; stride = HID_; col = n; }
    else if (n < HID_+1024)  { Wp = Wk; stride = 1024; col = n - HID_; }
    else                     { Wp = Wv; stride = 1024; col = n - HID_ - 1024; }
    __syncthreads();
    float acc[8] = {0,0,0,0,0,0,0,0};
    const float* wp = Wp + (size_t)k0 * stride + col;
    #pragma unroll 16
    for (int kk = 0; kk < CK_QKV; ++kk) {
        float w = ntload1(wp); wp += stride;
        float4 x0 = *(const float4*)&xs[kk*8];
        float4 x1 = *(const float4*)&xs[kk*8 + 4];
        acc[0] += x0.x*w; acc[1] += x0.y*w; acc[2] += x0.z*w; acc[3] += x0.w*w;
        acc[4] += x1.x*w; acc[5] += x1.y*w; acc[6] += x1.z*w; acc[7] += x1.w*w;
    }
    float* po = pout + (size_t)c * 8 * NCOL_QKV + n;
    #pragma unroll
    for (int b = 0; b < 8; ++b) po[(size_t)b*NCOL_QKV] = acc[b];
}

// ---------------- K1.5: combine qkv partials once -> qb (scaled), knv ----------------
__global__ __launch_bounds__(256) void k_qkv_comb(const float* __restrict__ pqkv,
        float* __restrict__ qb, float* __restrict__ knv) {
    const int tg = blockIdx.x*256 + threadIdx.x;   // 0..8191
    const float4* pq4 = (const float4*)pqkv;
    const float scale = 0.08838834764831845f;      // 1/sqrt(128)
    if (tg < 4096) {                       // q: b = tg>>9, float4-col = tg&511
        const int b = tg >> 9, c4 = tg & 511;
        float4 s = make_float4(0.f,0.f,0.f,0.f);
        for (int cc = 0; cc < KSP_QKV; ++cc) {
            float4 p = pq4[(size_t)(cc*8 + b)*(NCOL_QKV/4) + c4];
            s.x += p.x; s.y += p.y; s.z += p.z; s.w += p.w;
        }
        s.x*=scale; s.y*=scale; s.z*=scale; s.w*=scale;
        ((float4*)qb)[(size_t)b*512 + c4] = s;
    } else {                               // kn|vn per (b,hkv): 64 float4 each
        const int u2 = tg - 4096;
        const int b = u2 >> 9, r = u2 & 511;
        const int hkv = r >> 6, j = r & 63;
        const size_t cb4 = (j < 32) ? (size_t)(512 + hkv*32 + j)
                                    : (size_t)(768 + hkv*32 + (j - 32));
        float4 s = make_float4(0.f,0.f,0.f,0.f);
        for (int cc = 0; cc < KSP_QKV; ++cc) {
            float4 p = pq4[(size_t)(cc*8 + b)*(NCOL_QKV/4) + cb4];
            s.x += p.x; s.y += p.y; s.z += p.z; s.w += p.w;
        }
        ((float4*)knv)[(size_t)(b*8 + hkv)*64 + j] = s;
    }
}

// ---------------- K2: flash-decode attention, all-heads-per-block ----------------
// Block = (chunk of 32 tokens, batch). Thread t: hkv = t>>5, d-seg = t&31.
// One iteration's K load by the block = 4 KB CONTIGUOUS ([token][8 hkv][128 d]);
// a 16-token cache block streams as 64 KB contiguous. Each 32-lane group owns a
// complete (hkv, d-seg) output slice -> no cross-half-wave combine needed.
__global__ __launch_bounds__(256) void k_attn(const float* __restrict__ qb,
        const float* __restrict__ knv,
        const float* __restrict__ kc, const float* __restrict__ vc,
        const int* __restrict__ positions, const int* __restrict__ btab,
        float* __restrict__ pm, float* __restrict__ pl, float* __restrict__ pacc) {
    const int ch = blockIdx.x, b = blockIdx.y;
    const int pos = positions[b];
    const int c0  = ch * ACH;
    const int t = threadIdx.x;
    const int hkv = t >> 5, l32 = t & 31;
    const size_t pbase = (size_t)((b*HKV_ + hkv)*NACH + ch);
    if (c0 > pos) {
        if (l32 < 2) { pm[pbase*2 + l32] = -1e30f; pl[pbase*2 + l32] = 0.f; }
        #pragma unroll
        for (int g = 0; g < 2; ++g)
            *(float4*)&pacc[pbase*256 + g*128 + l32*4] = make_float4(0.f,0.f,0.f,0.f);
        return;
    }

    __shared__ int bts[ACH/BS_];
    if (t < ACH/BS_) bts[t] = btab[b*MAXB_ + ch*(ACH/BS_) + t];
    __syncthreads();

    const float4* qb4  = (const float4*)qb;
    const float4* knv4 = (const float4*)knv;
    float4 q0 = qb4[(size_t)b*512 + hkv*64 + l32];        // pre-scaled
    float4 q1 = qb4[(size_t)b*512 + hkv*64 + 32 + l32];

    float m0 = -1e30f, m1 = -1e30f, l0 = 0.f, l1 = 0.f;
    float a0[4] = {0,0,0,0}, a1[4] = {0,0,0,0};

    #pragma unroll 8
    for (int i = 0; i < ACH; ++i) {
        const int l = c0 + i;                     // token index, block-uniform
        const bool valid = (l <= pos);
        const float *kp, *vp;
        if (l == pos) {
            kp = (const float*)&knv4[(size_t)(b*8 + hkv)*64 + l32];
            vp = (const float*)&knv4[(size_t)(b*8 + hkv)*64 + 32 + l32];
        } else {
            size_t row = (size_t)bts[i >> 4] * BS_ + (i & (BS_-1));
            size_t off = row*(HKV_*D_) + hkv*D_ + l32*4;
            kp = kc + off;  vp = vc + off;
        }
        float4 kv = ntload4(kp);
        float4 vv = ntload4(vp);
        float s0 = q0.x*kv.x + q0.y*kv.y + q0.z*kv.z + q0.w*kv.w;
        float s1 = q1.x*kv.x + q1.y*kv.y + q1.z*kv.z + q1.w*kv.w;
        #pragma unroll
        for (int m = 16; m >= 1; m >>= 1) { s0 += __shfl_xor(s0, m); s1 += __shfl_xor(s1, m); }
        if (!valid) { s0 = -1e30f; s1 = -1e30f; }
        float nm0 = fmaxf(m0, s0);
        float cr0 = __expf(m0 - nm0);
        float p0  = valid ? __expf(s0 - nm0) : 0.f;
        m0 = nm0; l0 = l0*cr0 + p0;
        a0[0] = a0[0]*cr0 + p0*vv.x; a0[1] = a0[1]*cr0 + p0*vv.y;
        a0[2] = a0[2]*cr0 + p0*vv.z; a0[3] = a0[3]*cr0 + p0*vv.w;
        float nm1 = fmaxf(m1, s1);
        float cr1 = __expf(m1 - nm1);
        float p1  = valid ? __expf(s1 - nm1) : 0.f;
        m1 = nm1; l1 = l1*cr1 + p1;
        a1[0] = a1[0]*cr1 + p1*vv.x; a1[1] = a1[1]*cr1 + p1*vv.y;
        a1[2] = a1[2]*cr1 + p1*vv.z; a1[3] = a1[3]*cr1 + p1*vv.w;
    }

    *(float4*)&pacc[pbase*256 +   0 + l32*4] = make_float4(a0[0],a0[1],a0[2],a0[3]);
    *(float4*)&pacc[pbase*256 + 128 + l32*4] = make_float4(a1[0],a1[1],a1[2],a1[3]);
    if (l32 == 0) {
        pm[pbase*2 + 0] = m0; pl[pbase*2 + 0] = l0;
        pm[pbase*2 + 1] = m1; pl[pbase*2 + 1] = l1;
    }
}

// ---------------- K3: o_proj partials (inline attention combine, NACH chunks) ----------------
__global__ __launch_bounds__(256) void k_o_part(const float* __restrict__ pm,
        const float* __restrict__ pl, const float* __restrict__ pacc,
        const float* __restrict__ Wo, float* __restrict__ po) {
    const int cb   = blockIdx.y;            // 0..31
    const int head = cb >> 1;               // query head 0..15
    const int hkv  = head >> 1, g = head & 1;
    const int dhalf = (cb & 1) * 64;        // which 64 dims of the head
    const int t = threadIdx.x;
    const int n = blockIdx.x * 256 + t;     // 0..2047

    __shared__ float pms[8][NACH], pls[8][NACH];   // 4 KB each
    __shared__ float wch[8][NACH];
    __shared__ float wsum[8];
    __shared__ float xs[64 * 8];            // [kk][b]

    {   // load pm/pl for all (b, ch): 1024 values, 4 per thread
        #pragma unroll
        for (int r = 0; r < 4; ++r) {
            int id = t + r*256;             // 0..1023
            int bb = id >> 7, ch = id & 127;
            size_t ix = ((size_t)(bb*HKV_ + hkv)*NACH + ch)*2 + g;
            pms[bb][ch] = pm[ix];
            pls[bb][ch] = pl[ix];
        }
    }
    __syncthreads();
    if (t < 8) {
        float M = -1e30f;
        for (int ch = 0; ch < NACH; ++ch) M = fmaxf(M, pms[t][ch]);
        float Ls = 0.f;
        for (int ch = 0; ch < NACH; ++ch) {
            float w = __expf(pms[t][ch] - M);
            wch[t][ch] = w;
            Ls += w * pls[t][ch];
        }
        wsum[t] = 1.f / Ls;
    }
    __syncthreads();
    if (t < 128) {      // stage attn-out slice [8 b][64 d] via float4
        int bb = t >> 4, j = t & 15;
        float4 a = make_float4(0.f,0.f,0.f,0.f);
        size_t base4 = ((size_t)(bb*HKV_ + hkv)*NACH)*64 + (size_t)(g*128 + dhalf)/4 + j;
        for (int ch = 0; ch < NACH; ++ch) {
            float w = wch[bb][ch];
            float4 p = ((const float4*)pacc)[base4 + (size_t)ch*64];
            a.x += w*p.x; a.y += w*p.y; a.z += w*p.z; a.w += w*p.w;
        }
        float inv = wsum[bb];
        xs[(j*4+0)*8 + bb] = a.x*inv;
        xs[(j*4+1)*8 + bb] = a.y*inv;
        xs[(j*4+2)*8 + bb] = a.z*inv;
        xs[(j*4+3)*8 + bb] = a.w*inv;
    }
    __syncthreads();

    float acc[8] = {0,0,0,0,0,0,0,0};
    const float* wp = Wo + (size_t)(head*D_ + dhalf) * HID_ + n;
    #pragma unroll 16
    for (int kk = 0; kk < 64; ++kk) {
        float w = ntload1(wp); wp += HID_;
        float4 x0 = *(const float4*)&xs[kk*8];
        float4 x1 = *(const float4*)&xs[kk*8 + 4];
        acc[0] += x0.x*w; acc[1] += x0.y*w; acc[2] += x0.z*w; acc[3] += x0.w*w;
        acc[4] += x1.x*w; acc[5] += x1.y*w; acc[6] += x1.z*w; acc[7] += x1.w*w;
    }
    #pragma unroll
    for (int b = 0; b < 8; ++b) po[((size_t)cb*8 + b)*HID_ + n] = acc[b];
}

// ---------------- K4: lm_head partials (inline residual + po combine) ----------------
// Wlm loads CACHED (L3-persist across replays — round-6 win).
__global__ __launch_bounds__(256) void k_lm_part(const int* __restrict__ tokens,
        const float* __restrict__ embed, const float* __restrict__ po,
        const float* __restrict__ Wlm, float* __restrict__ plm) {
    __shared__ float xs[CK_LM * 8];         // [kk][b], 4 KB
    const int c  = blockIdx.y;
    const int k0 = c * CK_LM;
    const int t  = threadIdx.x;
    {   // stage y[b][k0..k0+128) = embed + sum of 32 po partials
        int bb = t >> 5, j = t & 31;        // j: float4 within 128 cols
        size_t col4 = (size_t)(k0 >> 2) + j;
        float4 a = ((const float4*)embed)[(size_t)tokens[bb]*(HID_/4) + col4];
        for (int c2 = 0; c2 < 32; ++c2) {
            float4 p = ((const float4*)po)[(size_t)(c2*8 + bb)*(HID_/4) + col4];
            a.x += p.x; a.y += p.y; a.z += p.z; a.w += p.w;
        }
        xs[(j*4+0)*8 + bb] = a.x;
        xs[(j*4+1)*8 + bb] = a.y;
        xs[(j*4+2)*8 + bb] = a.z;
        xs[(j*4+3)*8 + bb] = a.w;
    }
    __syncthreads();

    const int n0 = blockIdx.x * 1024 + t * 4;
    if (n0 >= VOCAB_) return;
    float4 acc[8];
    #pragma unroll
    for (int b = 0; b < 8; ++b) acc[b] = make_float4(0.f,0.f,0.f,0.f);
    const float* wp = Wlm + (size_t)k0 * VOCAB_ + n0;
    #pragma unroll 16
    for (int kk = 0; kk < CK_LM; ++kk) {
        float4 w = *(const float4*)wp; wp += VOCAB_;   // cached load (L3-persist)
        float4 x0 = *(const float4*)&xs[kk*8];
        float4 x1 = *(const float4*)&xs[kk*8 + 4];
        acc[0].x += x0.x*w.x; acc[0].y += x0.x*w.y; acc[0].z += x0.x*w.z; acc[0].w += x0.x*w.w;
        acc[1].x += x0.y*w.x; acc[1].y += x0.y*w.y; acc[1].z += x0.y*w.z; acc[1].w += x0.y*w.w;
        acc[2].x += x0.z*w.x; acc[2].y += x0.z*w.y; acc[2].z += x0.z*w.z; acc[2].w += x0.z*w.w;
        acc[3].x += x0.w*w.x; acc[3].y += x0.w*w.y; acc[3].z += x0.w*w.z; acc[3].w += x0.w*w.w;
        acc[4].x += x1.x*w.x; acc[4].y += x1.x*w.y; acc[4].z += x1.x*w.z; acc[4].w += x1.x*w.w;
        acc[5].x += x1.y*w.x; acc[5].y += x1.y*w.y; acc[5].z += x1.y*w.z; acc[5].w += x1.y*w.w;
        acc[6].x += x1.z*w.x; acc[6].y += x1.z*w.y; acc[6].z += x1.z*w.z; acc[6].w += x1.z*w.w;
        acc[7].x += x1.w*w.x; acc[7].y += x1.w*w.y; acc[7].z += x1.w*w.z; acc[7].w += x1.w*w.w;
    }
    #pragma unroll
    for (int b = 0; b < 8; ++b)
        *(float4*)&plm[(size_t)(c*8 + b)*VOCAB_ + n0] = acc[b];
}

// ---------------- K5: lm_head combine -> logits ----------------
__global__ __launch_bounds__(256) void k_lm_comb(const float* __restrict__ plm,
                                                 float* __restrict__ out) {
    const int b = blockIdx.y;
    const int n4 = blockIdx.x * 256 + threadIdx.x;
    if (n4 >= VOCAB_/4) return;
    float4 s = make_float4(0.f,0.f,0.f,0.f);
    #pragma unroll
    for (int c = 0; c < KSP_LM; ++c) {
        float4 p = ((const float4*)plm)[(size_t)(c*8 + b)*(VOCAB_/4) + n4];
        s.x += p.x; s.y += p.y; s.z += p.z; s.w += p.w;
    }
    ((float4*)out)[(size_t)b*(VOCAB_/4) + n4] = s;
}

extern "C" void kernel_launch(void* const* d_in, const int* in_sizes, int n_in,
                              void* d_out, int out_size, void* d_ws, size_t ws_size,
                              hipStream_t stream) {
    const int*   tokens    = (const int*)  d_in[0];
    const int*   positions = (const int*)  d_in[1];
    const int*   btab      = (const int*)  d_in[2];
    const float* kc        = (const float*)d_in[3];
    const float* vc        = (const float*)d_in[4];
    const float* embed     = (const float*)d_in[5];
    const float* Wq        = (const float*)d_in[6];
    const float* Wk        = (const float*)d_in[7];
    const float* Wv        = (const float*)d_in[8];
    const float* Wo        = (const float*)d_in[9];
    const float* Wlm       = (const float*)d_in[10];
    float* out = (float*)d_out;
    float* ws  = (float*)d_ws;

    float* pqkv = ws + OFF_PQKV;
    float* qb   = ws + OFF_QB;
    float* knv  = ws + OFF_KNV;
    float* pm   = ws + OFF_PM;
    float* pl   = ws + OFF_PL;
    float* pacc = ws + OFF_PACC;
    float* po   = ws + OFF_PO;
    float* plm  = ws + OFF_PLM;

    k_qkv_part<<<dim3(NCOL_QKV/256, KSP_QKV), 256, 0, stream>>>(tokens, embed, Wq, Wk, Wv, pqkv);
    k_qkv_comb<<<32, 256, 0, stream>>>(pqkv, qb, knv);
    k_attn    <<<dim3(NACH, B_), 256, 0, stream>>>(qb, knv, kc, vc, positions, btab,
                                                   pm, pl, pacc);
    k_o_part  <<<dim3(HID_/256, 32), 256, 0, stream>>>(pm, pl, pacc, Wo, po);
    k_lm_part <<<dim3((VOCAB_ + 1023)/1024, KSP_LM), 256, 0, stream>>>(tokens, embed, po, Wlm, plm);
    k_lm_comb <<<dim3((VOCAB_/4 + 255)/256, B_), 256, 0, stream>>>(plm, out);
}

// Round 11
// 112.171 us; speedup vs baseline: 1.1023x; 1.1023x over previous
//
#include <hip/hip_runtime.h>
#include <cstdint>
#include <cstddef>

// ---- problem constants ----
constexpr int B_    = 8;
constexpr int HKV_  = 8;
constexpr int G_    = 2;      // query heads per kv head
constexpr int D_    = 128;
constexpr int HID_  = 2048;
constexpr int VOCAB_= 32000;
constexpr int BS_   = 16;
constexpr int MAXB_ = 256;
constexpr int L_    = 4096;

// ---- tiling (round-6 best-measured config: 112.07 us) ----
constexpr int KSP_QKV = 32;  constexpr int CK_QKV = HID_ / KSP_QKV;  // 64
constexpr int KSP_O   = 32;                                          // 64 K-rows each
constexpr int KSP_LM  = 16;  constexpr int CK_LM  = HID_ / KSP_LM;   // 128
constexpr int CHUNK   = 128; constexpr int NCHUNK = L_ / CHUNK;      // 32
constexpr int NCOL_QKV = HID_ + 1024 + 1024;                         // 4096

// ---- workspace layout (floats) ----
constexpr size_t OFF_PQKV = 0;                                         // 32*8*4096
constexpr size_t OFF_PM   = OFF_PQKV + (size_t)KSP_QKV*B_*NCOL_QKV;
constexpr size_t OFF_PL   = OFF_PM   + (size_t)B_*HKV_*NCHUNK*G_;
constexpr size_t OFF_PACC = OFF_PL   + (size_t)B_*HKV_*NCHUNK*G_;
constexpr size_t OFF_PO   = OFF_PACC + (size_t)B_*HKV_*NCHUNK*G_*D_;
constexpr size_t OFF_PLM  = OFF_PO   + (size_t)KSP_O*B_*HID_;
// end = OFF_PLM + 16*8*32000 ~= 6.2M floats ~= 25 MB

// ---- nontemporal load helpers ----
// NT on streamed operands (KV cache, Wq/Wk/Wv/Wo) so they don't evict Wlm from
// the 256 MB L3; Wlm uses cached loads (L3-persist across replays — round-6 win).
typedef float f32x4_t __attribute__((ext_vector_type(4)));
__device__ __forceinline__ float4 ntload4(const float* p) {
    f32x4_t v = __builtin_nontemporal_load((const f32x4_t*)p);
    return make_float4(v.x, v.y, v.z, v.w);
}
__device__ __forceinline__ float ntload1(const float* p) {
    return __builtin_nontemporal_load(p);
}

// ---------------- K1: fused q/k/v projection partials ----------------
__global__ __launch_bounds__(256) void k_qkv_part(const int* __restrict__ tokens,
        const float* __restrict__ embed,
        const float* __restrict__ Wq, const float* __restrict__ Wk,
        const float* __restrict__ Wv, float* __restrict__ pout) {
    __shared__ float xs[CK_QKV * 8];           // [kk][b]
    const int c  = blockIdx.y;
    const int k0 = c * CK_QKV;
    const int n  = blockIdx.x * 256 + threadIdx.x;   // 0..4095
    for (int idx = threadIdx.x; idx < CK_QKV*8; idx += 256) {
        int b = idx >> 6, kk = idx & (CK_QKV-1);
        xs[kk*8 + b] = embed[(size_t)tokens[b]*HID_ + k0 + kk];
    }
    const float* Wp; int stride, col;
    if (n < HID_)            { Wp = Wq; stride = HID_; col = n; }
    else if (n < HID_+1024)  { Wp = Wk; stride = 1024; col = n - HID_; }
    else                     { Wp = Wv; stride = 1024; col = n - HID_ - 1024; }
    __syncthreads();
    float acc[8] = {0,0,0,0,0,0,0,0};
    const float* wp = Wp + (size_t)k0 * stride + col;
    #pragma unroll 16
    for (int kk = 0; kk < CK_QKV; ++kk) {
        float w = ntload1(wp); wp += stride;
        float4 x0 = *(const float4*)&xs[kk*8];
        float4 x1 = *(const float4*)&xs[kk*8 + 4];
        acc[0] += x0.x*w; acc[1] += x0.y*w; acc[2] += x0.z*w; acc[3] += x0.w*w;
        acc[4] += x1.x*w; acc[5] += x1.y*w; acc[6] += x1.z*w; acc[7] += x1.w*w;
    }
    float* po = pout + (size_t)c * 8 * NCOL_QKV + n;
    #pragma unroll
    for (int b = 0; b < 8; ++b) po[(size_t)b*NCOL_QKV] = acc[b];
}

// ---------------- K2: flash-decode attention (inline qkv combine) ----------------
__global__ __launch_bounds__(256) void k_attn(const float* __restrict__ pqkv,
        const float* __restrict__ kc, const float* __restrict__ vc,
        const int* __restrict__ positions, const int* __restrict__ btab,
        float* __restrict__ pm, float* __restrict__ pl, float* __restrict__ pacc) {
    const int ch = blockIdx.x, hkv = blockIdx.y, b = blockIdx.z;
    const int pos = positions[b];
    const int c0  = ch * CHUNK;
    const size_t pbase = (size_t)(b*HKV_ + hkv)*NCHUNK + ch;
    const int t = threadIdx.x;
    if (c0 > pos) {
        if (t < 2) { pm[pbase*2 + t] = -1e30f; pl[pbase*2 + t] = 0.f; }
        pacc[pbase*256 + t] = 0.f;
        return;
    }
    const bool haspos = (pos < c0 + CHUNK);   // c0 <= pos already

    __shared__ float qs[2*D_];      // combined+scaled q, [g][d]
    __shared__ float knvs[2*D_];    // combined kn|vn row for l==pos
    __shared__ int   bts[CHUNK/BS_];
    __shared__ float acc_l[8][256];
    __shared__ float ml_l[8][2][2];

    const float4* pq4 = (const float4*)pqkv;
    const float scale = 0.08838834764831845f;   // 1/sqrt(128)
    if (t < 64) {                   // q combine: 64 float4 = 256 floats
        float4 s = make_float4(0.f,0.f,0.f,0.f);
        size_t cb4 = (size_t)hkv*64 + t;        // (hkv*256)/4 + t
        for (int cc = 0; cc < KSP_QKV; ++cc) {
            float4 p = pq4[(size_t)(cc*8 + b)*(NCOL_QKV/4) + cb4];
            s.x += p.x; s.y += p.y; s.z += p.z; s.w += p.w;
        }
        s.x *= scale; s.y *= scale; s.z *= scale; s.w *= scale;
        ((float4*)qs)[t] = s;
    } else if (t < 128 && haspos) { // kn|vn combine: 64 float4
        int j = t - 64;
        size_t cb4 = (j < 32) ? (size_t)(HID_ + hkv*D_)/4 + j
                              : (size_t)(HID_ + 1024 + hkv*D_)/4 + (j - 32);
        float4 s = make_float4(0.f,0.f,0.f,0.f);
        for (int cc = 0; cc < KSP_QKV; ++cc) {
            float4 p = pq4[(size_t)(cc*8 + b)*(NCOL_QKV/4) + cb4];
            s.x += p.x; s.y += p.y; s.z += p.z; s.w += p.w;
        }
        ((float4*)knvs)[j] = s;
    }
    if (t < CHUNK/BS_) bts[t] = btab[b*MAXB_ + ch*(CHUNK/BS_) + t];
    __syncthreads();

    const int hw = t >> 5, l32 = t & 31;
    float4 q0 = ((const float4*)qs)[l32];
    float4 q1 = ((const float4*)qs)[32 + l32];

    float m0 = -1e30f, m1 = -1e30f, l0 = 0.f, l1 = 0.f;
    float a0[4] = {0,0,0,0}, a1[4] = {0,0,0,0};

    #pragma unroll 8
    for (int i = 0; i < CHUNK/8; ++i) {
        const int lo = i*8 + hw;                 // offset in chunk, uniform per half-wave
        const int l  = c0 + lo;
        const bool valid = (l < pos);            // l==pos handled separately
        size_t row = (size_t)bts[lo >> 4] * BS_ + (lo & (BS_-1));
        size_t off = (row*HKV_ + hkv)*D_ + l32*4;
        float4 kv = ntload4(kc + off);
        float4 vv = ntload4(vc + off);
        float s0 = q0.x*kv.x + q0.y*kv.y + q0.z*kv.z + q0.w*kv.w;
        float s1 = q1.x*kv.x + q1.y*kv.y + q1.z*kv.z + q1.w*kv.w;
        #pragma unroll
        for (int m = 16; m >= 1; m >>= 1) { s0 += __shfl_xor(s0, m); s1 += __shfl_xor(s1, m); }
        if (!valid) { s0 = -1e30f; s1 = -1e30f; }
        float nm0 = fmaxf(m0, s0);
        float cr0 = __expf(m0 - nm0);
        float p0  = valid ? __expf(s0 - nm0) : 0.f;
        m0 = nm0; l0 = l0*cr0 + p0;
        a0[0] = a0[0]*cr0 + p0*vv.x; a0[1] = a0[1]*cr0 + p0*vv.y;
        a0[2] = a0[2]*cr0 + p0*vv.z; a0[3] = a0[3]*cr0 + p0*vv.w;
        float nm1 = fmaxf(m1, s1);
        float cr1 = __expf(m1 - nm1);
        float p1  = valid ? __expf(s1 - nm1) : 0.f;
        m1 = nm1; l1 = l1*cr1 + p1;
        a1[0] = a1[0]*cr1 + p1*vv.x; a1[1] = a1[1]*cr1 + p1*vv.y;
        a1[2] = a1[2]*cr1 + p1*vv.z; a1[3] = a1[3]*cr1 + p1*vv.w;
    }

    // new-token update (cache value at slot is stale; use combined kn/vn)
    if (haspos && hw == 0) {
        float4 kv = ((const float4*)knvs)[l32];
        float4 vv = ((const float4*)knvs)[32 + l32];
        float s0 = q0.x*kv.x + q0.y*kv.y + q0.z*kv.z + q0.w*kv.w;
        float s1 = q1.x*kv.x + q1.y*kv.y + q1.z*kv.z + q1.w*kv.w;
        #pragma unroll
        for (int m = 16; m >= 1; m >>= 1) { s0 += __shfl_xor(s0, m); s1 += __shfl_xor(s1, m); }
        float nm0 = fmaxf(m0, s0);
        float cr0 = __expf(m0 - nm0);
        float p0  = __expf(s0 - nm0);
        m0 = nm0; l0 = l0*cr0 + p0;
        a0[0] = a0[0]*cr0 + p0*vv.x; a0[1] = a0[1]*cr0 + p0*vv.y;
        a0[2] = a0[2]*cr0 + p0*vv.z; a0[3] = a0[3]*cr0 + p0*vv.w;
        float nm1 = fmaxf(m1, s1);
        float cr1 = __expf(m1 - nm1);
        float p1  = __expf(s1 - nm1);
        m1 = nm1; l1 = l1*cr1 + p1;
        a1[0] = a1[0]*cr1 + p1*vv.x; a1[1] = a1[1]*cr1 + p1*vv.y;
        a1[2] = a1[2]*cr1 + p1*vv.z; a1[3] = a1[3]*cr1 + p1*vv.w;
    }

    *(float4*)&acc_l[hw][0*D_ + l32*4] = make_float4(a0[0],a0[1],a0[2],a0[3]);
    *(float4*)&acc_l[hw][1*D_ + l32*4] = make_float4(a1[0],a1[1],a1[2],a1[3]);
    if (l32 == 0) {
        ml_l[hw][0][0] = m0; ml_l[hw][0][1] = l0;
        ml_l[hw][1][0] = m1; ml_l[hw][1][1] = l1;
    }
    __syncthreads();

    const int g = t >> 7, d = t & 127;
    float M = -1e30f;
    #pragma unroll
    for (int h = 0; h < 8; ++h) M = fmaxf(M, ml_l[h][g][0]);
    float Ls = 0.f, val = 0.f;
    #pragma unroll
    for (int h = 0; h < 8; ++h) {
        float w = __expf(ml_l[h][g][0] - M);
        Ls  += w * ml_l[h][g][1];
        val += w * acc_l[h][g*D_ + d];
    }
    pacc[pbase*256 + t] = val;
    if (d == 0) { pm[pbase*2 + g] = M; pl[pbase*2 + g] = Ls; }
}

// ---------------- K3: o_proj partials (inline attention combine) ----------------
__global__ __launch_bounds__(256) void k_o_part(const float* __restrict__ pm,
        const float* __restrict__ pl, const float* __restrict__ pacc,
        const float* __restrict__ Wo, float* __restrict__ po) {
    const int cb   = blockIdx.y;            // 0..31
    const int head = cb >> 1;               // query head 0..15
    const int hkv  = head >> 1, g = head & 1;
    const int dhalf = (cb & 1) * 64;        // which 64 dims of the head
    const int t = threadIdx.x;
    const int n = blockIdx.x * 256 + t;     // 0..2047

    __shared__ float pms[8][NCHUNK], pls[8][NCHUNK];
    __shared__ float wch[8][NCHUNK];
    __shared__ float wsum[8];
    __shared__ float xs[64 * 8];            // [kk][b]

    {   // load pm/pl for all (b, ch)
        int bb = t >> 5, ch = t & 31;
        size_t ix = ((size_t)(bb*HKV_ + hkv)*NCHUNK + ch)*2 + g;
        pms[bb][ch] = pm[ix];
        pls[bb][ch] = pl[ix];
    }
    __syncthreads();
    if (t < 8) {
        float M = -1e30f;
        for (int ch = 0; ch < NCHUNK; ++ch) M = fmaxf(M, pms[t][ch]);
        float Ls = 0.f;
        for (int ch = 0; ch < NCHUNK; ++ch) {
            float w = __expf(pms[t][ch] - M);
            wch[t][ch] = w;
            Ls += w * pls[t][ch];
        }
        wsum[t] = 1.f / Ls;
    }
    __syncthreads();
    if (t < 128) {      // stage attn-out slice [8 b][64 d] via float4
        int bb = t >> 4, j = t & 15;
        float4 a = make_float4(0.f,0.f,0.f,0.f);
        size_t base4 = ((size_t)(bb*HKV_ + hkv)*NCHUNK)*64 + (size_t)(g*128 + dhalf)/4 + j;
        for (int ch = 0; ch < NCHUNK; ++ch) {
            float w = wch[bb][ch];
            float4 p = ((const float4*)pacc)[base4 + (size_t)ch*64];
            a.x += w*p.x; a.y += w*p.y; a.z += w*p.z; a.w += w*p.w;
        }
        float inv = wsum[bb];
        xs[(j*4+0)*8 + bb] = a.x*inv;
        xs[(j*4+1)*8 + bb] = a.y*inv;
        xs[(j*4+2)*8 + bb] = a.z*inv;
        xs[(j*4+3)*8 + bb] = a.w*inv;
    }
    __syncthreads();

    float acc[8] = {0,0,0,0,0,0,0,0};
    const float* wp = Wo + (size_t)(head*D_ + dhalf) * HID_ + n;
    #pragma unroll 16
    for (int kk = 0; kk < 64; ++kk) {
        float w = ntload1(wp); wp += HID_;
        float4 x0 = *(const float4*)&xs[kk*8];
        float4 x1 = *(const float4*)&xs[kk*8 + 4];
        acc[0] += x0.x*w; acc[1] += x0.y*w; acc[2] += x0.z*w; acc[3] += x0.w*w;
        acc[4] += x1.x*w; acc[5] += x1.y*w; acc[6] += x1.z*w; acc[7] += x1.w*w;
    }
    #pragma unroll
    for (int b = 0; b < 8; ++b) po[((size_t)cb*8 + b)*HID_ + n] = acc[b];
}

// ---------------- K4: lm_head partials (inline residual + po combine) ----------------
// Wlm loads CACHED (not NT): Wlm is 256 MB = L3 size and is re-read every
// replay — letting it persist in Infinity Cache is the round-6 win.
__global__ __launch_bounds__(256) void k_lm_part(const int* __restrict__ tokens,
        const float* __restrict__ embed, const float* __restrict__ po,
        const float* __restrict__ Wlm, float* __restrict__ plm) {
    __shared__ float xs[CK_LM * 8];         // [kk][b], 4 KB
    const int c  = blockIdx.y;
    const int k0 = c * CK_LM;
    const int t  = threadIdx.x;
    {   // stage y[b][k0..k0+128) = embed + sum of 32 po partials
        int bb = t >> 5, j = t & 31;        // j: float4 within 128 cols
        size_t col4 = (size_t)(k0 >> 2) + j;
        float4 a = ((const float4*)embed)[(size_t)tokens[bb]*(HID_/4) + col4];
        for (int c2 = 0; c2 < KSP_O; ++c2) {
            float4 p = ((const float4*)po)[(size_t)(c2*8 + bb)*(HID_/4) + col4];
            a.x += p.x; a.y += p.y; a.z += p.z; a.w += p.w;
        }
        xs[(j*4+0)*8 + bb] = a.x;
        xs[(j*4+1)*8 + bb] = a.y;
        xs[(j*4+2)*8 + bb] = a.z;
        xs[(j*4+3)*8 + bb] = a.w;
    }
    __syncthreads();

    const int n0 = blockIdx.x * 1024 + t * 4;
    if (n0 >= VOCAB_) return;
    float4 acc[8];
    #pragma unroll
    for (int b = 0; b < 8; ++b) acc[b] = make_float4(0.f,0.f,0.f,0.f);
    const float* wp = Wlm + (size_t)k0 * VOCAB_ + n0;
    #pragma unroll 8
    for (int kk = 0; kk < CK_LM; ++kk) {
        float4 w = *(const float4*)wp; wp += VOCAB_;   // cached load (L3-persist)
        float4 x0 = *(const float4*)&xs[kk*8];
        float4 x1 = *(const float4*)&xs[kk*8 + 4];
        acc[0].x += x0.x*w.x; acc[0].y += x0.x*w.y; acc[0].z += x0.x*w.z; acc[0].w += x0.x*w.w;
        acc[1].x += x0.y*w.x; acc[1].y += x0.y*w.y; acc[1].z += x0.y*w.z; acc[1].w += x0.y*w.w;
        acc[2].x += x0.z*w.x; acc[2].y += x0.z*w.y; acc[2].z += x0.z*w.z; acc[2].w += x0.z*w.w;
        acc[3].x += x0.w*w.x; acc[3].y += x0.w*w.y; acc[3].z += x0.w*w.z; acc[3].w += x0.w*w.w;
        acc[4].x += x1.x*w.x; acc[4].y += x1.x*w.y; acc[4].z += x1.x*w.z; acc[4].w += x1.x*w.w;
        acc[5].x += x1.y*w.x; acc[5].y += x1.y*w.y; acc[5].z += x1.y*w.z; acc[5].w += x1.y*w.w;
        acc[6].x += x1.z*w.x; acc[6].y += x1.z*w.y; acc[6].z += x1.z*w.z; acc[6].w += x1.z*w.w;
        acc[7].x += x1.w*w.x; acc[7].y += x1.w*w.y; acc[7].z += x1.w*w.z; acc[7].w += x1.w*w.w;
    }
    #pragma unroll
    for (int b = 0; b < 8; ++b)
        *(float4*)&plm[(size_t)(c*8 + b)*VOCAB_ + n0] = acc[b];
}

// ---------------- K5: lm_head combine -> logits ----------------
__global__ __launch_bounds__(256) void k_lm_comb(const float* __restrict__ plm,
                                                 float* __restrict__ out) {
    const int b = blockIdx.y;
    const int n4 = blockIdx.x * 256 + threadIdx.x;
    if (n4 >= VOCAB_/4) return;
    float4 s = make_float4(0.f,0.f,0.f,0.f);
    #pragma unroll
    for (int c = 0; c < KSP_LM; ++c) {
        float4 p = ((const float4*)plm)[(size_t)(c*8 + b)*(VOCAB_/4) + n4];
        s.x += p.x; s.y += p.y; s.z += p.z; s.w += p.w;
    }
    ((float4*)out)[(size_t)b*(VOCAB_/4) + n4] = s;
}

extern "C" void kernel_launch(void* const* d_in, const int* in_sizes, int n_in,
                              void* d_out, int out_size, void* d_ws, size_t ws_size,
                              hipStream_t stream) {
    const int*   tokens    = (const int*)  d_in[0];
    const int*   positions = (const int*)  d_in[1];
    const int*   btab      = (const int*)  d_in[2];
    const float* kc        = (const float*)d_in[3];
    const float* vc        = (const float*)d_in[4];
    const float* embed     = (const float*)d_in[5];
    const float* Wq        = (const float*)d_in[6];
    const float* Wk        = (const float*)d_in[7];
    const float* Wv        = (const float*)d_in[8];
    const float* Wo        = (const float*)d_in[9];
    const float* Wlm       = (const float*)d_in[10];
    float* out = (float*)d_out;
    float* ws  = (float*)d_ws;

    float* pqkv = ws + OFF_PQKV;
    float* pm   = ws + OFF_PM;
    float* pl   = ws + OFF_PL;
    float* pacc = ws + OFF_PACC;
    float* po   = ws + OFF_PO;
    float* plm  = ws + OFF_PLM;

    k_qkv_part<<<dim3(NCOL_QKV/256, KSP_QKV), 256, 0, stream>>>(tokens, embed, Wq, Wk, Wv, pqkv);
    k_attn    <<<dim3(NCHUNK, HKV_, B_), 256, 0, stream>>>(pqkv, kc, vc, positions, btab,
                                                           pm, pl, pacc);
    k_o_part  <<<dim3(HID_/256, KSP_O), 256, 0, stream>>>(pm, pl, pacc, Wo, po);
    k_lm_part <<<dim3((VOCAB_ + 1023)/1024, KSP_LM), 256, 0, stream>>>(tokens, embed, po, Wlm, plm);
    k_lm_comb <<<dim3((VOCAB_/4 + 255)/256, B_), 256, 0, stream>>>(plm, out);
}

// Round 12
// 111.070 us; speedup vs baseline: 1.1133x; 1.0099x over previous
//
#include <hip/hip_runtime.h>
#include <cstdint>
#include <cstddef>

// ---- problem constants ----
constexpr int B_    = 8;
constexpr int HKV_  = 8;
constexpr int G_    = 2;      // query heads per kv head
constexpr int D_    = 128;
constexpr int HID_  = 2048;
constexpr int VOCAB_= 32000;
constexpr int BS_   = 16;
constexpr int MAXB_ = 256;
constexpr int L_    = 4096;

// ---- tiling (round-6 config; CHUNK 128->64 this round) ----
constexpr int KSP_QKV = 32;  constexpr int CK_QKV = HID_ / KSP_QKV;  // 64
constexpr int KSP_O   = 32;                                          // 64 K-rows each
constexpr int KSP_LM  = 16;  constexpr int CK_LM  = HID_ / KSP_LM;   // 128
constexpr int CHUNK   = 64;  constexpr int NCHUNK = L_ / CHUNK;      // 64
constexpr int NCOL_QKV = HID_ + 1024 + 1024;                         // 4096

// ---- workspace layout (floats) ----
constexpr size_t OFF_PQKV = 0;                                         // 32*8*4096
constexpr size_t OFF_PM   = OFF_PQKV + (size_t)KSP_QKV*B_*NCOL_QKV;
constexpr size_t OFF_PL   = OFF_PM   + (size_t)B_*HKV_*NCHUNK*G_;
constexpr size_t OFF_PACC = OFF_PL   + (size_t)B_*HKV_*NCHUNK*G_;
constexpr size_t OFF_PO   = OFF_PACC + (size_t)B_*HKV_*NCHUNK*G_*D_;
constexpr size_t OFF_PLM  = OFF_PO   + (size_t)KSP_O*B_*HID_;
// end = OFF_PLM + 16*8*32000 ~= 6.8M floats ~= 27 MB

// ---- nontemporal load helpers ----
// NT on streamed operands (KV cache, Wq/Wk/Wv/Wo) so they don't evict Wlm from
// the 256 MB L3; Wlm uses cached loads (L3-persist across replays — round-6 win).
typedef float f32x4_t __attribute__((ext_vector_type(4)));
__device__ __forceinline__ float4 ntload4(const float* p) {
    f32x4_t v = __builtin_nontemporal_load((const f32x4_t*)p);
    return make_float4(v.x, v.y, v.z, v.w);
}
__device__ __forceinline__ float ntload1(const float* p) {
    return __builtin_nontemporal_load(p);
}

// ---------------- K1: fused q/k/v projection partials ----------------
__global__ __launch_bounds__(256) void k_qkv_part(const int* __restrict__ tokens,
        const float* __restrict__ embed,
        const float* __restrict__ Wq, const float* __restrict__ Wk,
        const float* __restrict__ Wv, float* __restrict__ pout) {
    __shared__ float xs[CK_QKV * 8];           // [kk][b]
    const int c  = blockIdx.y;
    const int k0 = c * CK_QKV;
    const int n  = blockIdx.x * 256 + threadIdx.x;   // 0..4095
    for (int idx = threadIdx.x; idx < CK_QKV*8; idx += 256) {
        int b = idx >> 6, kk = idx & (CK_QKV-1);
        xs[kk*8 + b] = embed[(size_t)tokens[b]*HID_ + k0 + kk];
    }
    const float* Wp; int stride, col;
    if (n < HID_)            { Wp = Wq; stride = HID_; col = n; }
    else if (n < HID_+1024)  { Wp = Wk; stride = 1024; col = n - HID_; }
    else                     { Wp = Wv; stride = 1024; col = n - HID_ - 1024; }
    __syncthreads();
    float acc[8] = {0,0,0,0,0,0,0,0};
    const float* wp = Wp + (size_t)k0 * stride + col;
    #pragma unroll 16
    for (int kk = 0; kk < CK_QKV; ++kk) {
        float w = ntload1(wp); wp += stride;
        float4 x0 = *(const float4*)&xs[kk*8];
        float4 x1 = *(const float4*)&xs[kk*8 + 4];
        acc[0] += x0.x*w; acc[1] += x0.y*w; acc[2] += x0.z*w; acc[3] += x0.w*w;
        acc[4] += x1.x*w; acc[5] += x1.y*w; acc[6] += x1.z*w; acc[7] += x1.w*w;
    }
    float* po = pout + (size_t)c * 8 * NCOL_QKV + n;
    #pragma unroll
    for (int b = 0; b < 8; ++b) po[(size_t)b*NCOL_QKV] = acc[b];
}

// ---------------- K2: flash-decode attention (inline qkv combine) ----------------
__global__ __launch_bounds__(256) void k_attn(const float* __restrict__ pqkv,
        const float* __restrict__ kc, const float* __restrict__ vc,
        const int* __restrict__ positions, const int* __restrict__ btab,
        float* __restrict__ pm, float* __restrict__ pl, float* __restrict__ pacc) {
    const int ch = blockIdx.x, hkv = blockIdx.y, b = blockIdx.z;
    const int pos = positions[b];
    const int c0  = ch * CHUNK;
    const size_t pbase = (size_t)(b*HKV_ + hkv)*NCHUNK + ch;
    const int t = threadIdx.x;
    if (c0 > pos) {
        if (t < 2) { pm[pbase*2 + t] = -1e30f; pl[pbase*2 + t] = 0.f; }
        pacc[pbase*256 + t] = 0.f;
        return;
    }
    const bool haspos = (pos < c0 + CHUNK);   // c0 <= pos already

    __shared__ float qs[2*D_];      // combined+scaled q, [g][d]
    __shared__ float knvs[2*D_];    // combined kn|vn row for l==pos
    __shared__ int   bts[CHUNK/BS_];
    __shared__ float acc_l[8][256];
    __shared__ float ml_l[8][2][2];

    const float4* pq4 = (const float4*)pqkv;
    const float scale = 0.08838834764831845f;   // 1/sqrt(128)
    if (t < 64) {                   // q combine: 64 float4 = 256 floats
        float4 s = make_float4(0.f,0.f,0.f,0.f);
        size_t cb4 = (size_t)hkv*64 + t;        // (hkv*256)/4 + t
        for (int cc = 0; cc < KSP_QKV; ++cc) {
            float4 p = pq4[(size_t)(cc*8 + b)*(NCOL_QKV/4) + cb4];
            s.x += p.x; s.y += p.y; s.z += p.z; s.w += p.w;
        }
        s.x *= scale; s.y *= scale; s.z *= scale; s.w *= scale;
        ((float4*)qs)[t] = s;
    } else if (t < 128 && haspos) { // kn|vn combine: 64 float4
        int j = t - 64;
        size_t cb4 = (j < 32) ? (size_t)(HID_ + hkv*D_)/4 + j
                              : (size_t)(HID_ + 1024 + hkv*D_)/4 + (j - 32);
        float4 s = make_float4(0.f,0.f,0.f,0.f);
        for (int cc = 0; cc < KSP_QKV; ++cc) {
            float4 p = pq4[(size_t)(cc*8 + b)*(NCOL_QKV/4) + cb4];
            s.x += p.x; s.y += p.y; s.z += p.z; s.w += p.w;
        }
        ((float4*)knvs)[j] = s;
    }
    if (t < CHUNK/BS_) bts[t] = btab[b*MAXB_ + ch*(CHUNK/BS_) + t];
    __syncthreads();

    const int hw = t >> 5, l32 = t & 31;
    float4 q0 = ((const float4*)qs)[l32];
    float4 q1 = ((const float4*)qs)[32 + l32];

    float m0 = -1e30f, m1 = -1e30f, l0 = 0.f, l1 = 0.f;
    float a0[4] = {0,0,0,0}, a1[4] = {0,0,0,0};

    #pragma unroll 8
    for (int i = 0; i < CHUNK/8; ++i) {
        const int lo = i*8 + hw;                 // offset in chunk, uniform per half-wave
        const int l  = c0 + lo;
        const bool valid = (l < pos);            // l==pos handled separately
        size_t row = (size_t)bts[lo >> 4] * BS_ + (lo & (BS_-1));
        size_t off = (row*HKV_ + hkv)*D_ + l32*4;
        float4 kv = ntload4(kc + off);
        float4 vv = ntload4(vc + off);
        float s0 = q0.x*kv.x + q0.y*kv.y + q0.z*kv.z + q0.w*kv.w;
        float s1 = q1.x*kv.x + q1.y*kv.y + q1.z*kv.z + q1.w*kv.w;
        #pragma unroll
        for (int m = 16; m >= 1; m >>= 1) { s0 += __shfl_xor(s0, m); s1 += __shfl_xor(s1, m); }
        if (!valid) { s0 = -1e30f; s1 = -1e30f; }
        float nm0 = fmaxf(m0, s0);
        float cr0 = __expf(m0 - nm0);
        float p0  = valid ? __expf(s0 - nm0) : 0.f;
        m0 = nm0; l0 = l0*cr0 + p0;
        a0[0] = a0[0]*cr0 + p0*vv.x; a0[1] = a0[1]*cr0 + p0*vv.y;
        a0[2] = a0[2]*cr0 + p0*vv.z; a0[3] = a0[3]*cr0 + p0*vv.w;
        float nm1 = fmaxf(m1, s1);
        float cr1 = __expf(m1 - nm1);
        float p1  = valid ? __expf(s1 - nm1) : 0.f;
        m1 = nm1; l1 = l1*cr1 + p1;
        a1[0] = a1[0]*cr1 + p1*vv.x; a1[1] = a1[1]*cr1 + p1*vv.y;
        a1[2] = a1[2]*cr1 + p1*vv.z; a1[3] = a1[3]*cr1 + p1*vv.w;
    }

    // new-token update (cache value at slot is stale; use combined kn/vn)
    if (haspos && hw == 0) {
        float4 kv = ((const float4*)knvs)[l32];
        float4 vv = ((const float4*)knvs)[32 + l32];
        float s0 = q0.x*kv.x + q0.y*kv.y + q0.z*kv.z + q0.w*kv.w;
        float s1 = q1.x*kv.x + q1.y*kv.y + q1.z*kv.z + q1.w*kv.w;
        #pragma unroll
        for (int m = 16; m >= 1; m >>= 1) { s0 += __shfl_xor(s0, m); s1 += __shfl_xor(s1, m); }
        float nm0 = fmaxf(m0, s0);
        float cr0 = __expf(m0 - nm0);
        float p0  = __expf(s0 - nm0);
        m0 = nm0; l0 = l0*cr0 + p0;
        a0[0] = a0[0]*cr0 + p0*vv.x; a0[1] = a0[1]*cr0 + p0*vv.y;
        a0[2] = a0[2]*cr0 + p0*vv.z; a0[3] = a0[3]*cr0 + p0*vv.w;
        float nm1 = fmaxf(m1, s1);
        float cr1 = __expf(m1 - nm1);
        float p1  = __expf(s1 - nm1);
        m1 = nm1; l1 = l1*cr1 + p1;
        a1[0] = a1[0]*cr1 + p1*vv.x; a1[1] = a1[1]*cr1 + p1*vv.y;
        a1[2] = a1[2]*cr1 + p1*vv.z; a1[3] = a1[3]*cr1 + p1*vv.w;
    }

    *(float4*)&acc_l[hw][0*D_ + l32*4] = make_float4(a0[0],a0[1],a0[2],a0[3]);
    *(float4*)&acc_l[hw][1*D_ + l32*4] = make_float4(a1[0],a1[1],a1[2],a1[3]);
    if (l32 == 0) {
        ml_l[hw][0][0] = m0; ml_l[hw][0][1] = l0;
        ml_l[hw][1][0] = m1; ml_l[hw][1][1] = l1;
    }
    __syncthreads();

    const int g = t >> 7, d = t & 127;
    float M = -1e30f;
    #pragma unroll
    for (int h = 0; h < 8; ++h) M = fmaxf(M, ml_l[h][g][0]);
    float Ls = 0.f, val = 0.f;
    #pragma unroll
    for (int h = 0; h < 8; ++h) {
        float w = __expf(ml_l[h][g][0] - M);
        Ls  += w * ml_l[h][g][1];
        val += w * acc_l[h][g*D_ + d];
    }
    pacc[pbase*256 + t] = val;
    if (d == 0) { pm[pbase*2 + g] = M; pl[pbase*2 + g] = Ls; }
}

// ---------------- K3: o_proj partials (inline attention combine) ----------------
__global__ __launch_bounds__(256) void k_o_part(const float* __restrict__ pm,
        const float* __restrict__ pl, const float* __restrict__ pacc,
        const float* __restrict__ Wo, float* __restrict__ po) {
    const int cb   = blockIdx.y;            // 0..31
    const int head = cb >> 1;               // query head 0..15
    const int hkv  = head >> 1, g = head & 1;
    const int dhalf = (cb & 1) * 64;        // which 64 dims of the head
    const int t = threadIdx.x;
    const int n = blockIdx.x * 256 + t;     // 0..2047

    __shared__ float pms[8][NCHUNK], pls[8][NCHUNK];   // 2 KB each (NCHUNK=64)
    __shared__ float wch[8][NCHUNK];
    __shared__ float wsum[8];
    __shared__ float xs[64 * 8];            // [kk][b]

    {   // load pm/pl for all (b, ch): 8*64 = 512 entries, 2 per thread
        #pragma unroll
        for (int r = 0; r < 2; ++r) {
            int id = t + r*256;             // 0..511
            int bb = id >> 6, ch = id & 63;
            size_t ix = ((size_t)(bb*HKV_ + hkv)*NCHUNK + ch)*2 + g;
            pms[bb][ch] = pm[ix];
            pls[bb][ch] = pl[ix];
        }
    }
    __syncthreads();
    if (t < 8) {
        float M = -1e30f;
        for (int ch = 0; ch < NCHUNK; ++ch) M = fmaxf(M, pms[t][ch]);
        float Ls = 0.f;
        for (int ch = 0; ch < NCHUNK; ++ch) {
            float w = __expf(pms[t][ch] - M);
            wch[t][ch] = w;
            Ls += w * pls[t][ch];
        }
        wsum[t] = 1.f / Ls;
    }
    __syncthreads();
    if (t < 128) {      // stage attn-out slice [8 b][64 d] via float4
        int bb = t >> 4, j = t & 15;
        float4 a = make_float4(0.f,0.f,0.f,0.f);
        size_t base4 = ((size_t)(bb*HKV_ + hkv)*NCHUNK)*64 + (size_t)(g*128 + dhalf)/4 + j;
        for (int ch = 0; ch < NCHUNK; ++ch) {
            float w = wch[bb][ch];
            float4 p = ((const float4*)pacc)[base4 + (size_t)ch*64];
            a.x += w*p.x; a.y += w*p.y; a.z += w*p.z; a.w += w*p.w;
        }
        float inv = wsum[bb];
        xs[(j*4+0)*8 + bb] = a.x*inv;
        xs[(j*4+1)*8 + bb] = a.y*inv;
        xs[(j*4+2)*8 + bb] = a.z*inv;
        xs[(j*4+3)*8 + bb] = a.w*inv;
    }
    __syncthreads();

    float acc[8] = {0,0,0,0,0,0,0,0};
    const float* wp = Wo + (size_t)(head*D_ + dhalf) * HID_ + n;
    #pragma unroll 16
    for (int kk = 0; kk < 64; ++kk) {
        float w = ntload1(wp); wp += HID_;
        float4 x0 = *(const float4*)&xs[kk*8];
        float4 x1 = *(const float4*)&xs[kk*8 + 4];
        acc[0] += x0.x*w; acc[1] += x0.y*w; acc[2] += x0.z*w; acc[3] += x0.w*w;
        acc[4] += x1.x*w; acc[5] += x1.y*w; acc[6] += x1.z*w; acc[7] += x1.w*w;
    }
    #pragma unroll
    for (int b = 0; b < 8; ++b) po[((size_t)cb*8 + b)*HID_ + n] = acc[b];
}

// ---------------- K4: lm_head partials (inline residual + po combine) ----------------
// Wlm loads CACHED (not NT): Wlm is 256 MB = L3 size and is re-read every
// replay — letting it persist in Infinity Cache is the round-6 win.
__global__ __launch_bounds__(256) void k_lm_part(const int* __restrict__ tokens,
        const float* __restrict__ embed, const float* __restrict__ po,
        const float* __restrict__ Wlm, float* __restrict__ plm) {
    __shared__ float xs[CK_LM * 8];         // [kk][b], 4 KB
    const int c  = blockIdx.y;
    const int k0 = c * CK_LM;
    const int t  = threadIdx.x;
    {   // stage y[b][k0..k0+128) = embed + sum of 32 po partials
        int bb = t >> 5, j = t & 31;        // j: float4 within 128 cols
        size_t col4 = (size_t)(k0 >> 2) + j;
        float4 a = ((const float4*)embed)[(size_t)tokens[bb]*(HID_/4) + col4];
        for (int c2 = 0; c2 < KSP_O; ++c2) {
            float4 p = ((const float4*)po)[(size_t)(c2*8 + bb)*(HID_/4) + col4];
            a.x += p.x; a.y += p.y; a.z += p.z; a.w += p.w;
        }
        xs[(j*4+0)*8 + bb] = a.x;
        xs[(j*4+1)*8 + bb] = a.y;
        xs[(j*4+2)*8 + bb] = a.z;
        xs[(j*4+3)*8 + bb] = a.w;
    }
    __syncthreads();

    const int n0 = blockIdx.x * 1024 + t * 4;
    if (n0 >= VOCAB_) return;
    float4 acc[8];
    #pragma unroll
    for (int b = 0; b < 8; ++b) acc[b] = make_float4(0.f,0.f,0.f,0.f);
    const float* wp = Wlm + (size_t)k0 * VOCAB_ + n0;
    #pragma unroll 8
    for (int kk = 0; kk < CK_LM; ++kk) {
        float4 w = *(const float4*)wp; wp += VOCAB_;   // cached load (L3-persist)
        float4 x0 = *(const float4*)&xs[kk*8];
        float4 x1 = *(const float4*)&xs[kk*8 + 4];
        acc[0].x += x0.x*w.x; acc[0].y += x0.x*w.y; acc[0].z += x0.x*w.z; acc[0].w += x0.x*w.w;
        acc[1].x += x0.y*w.x; acc[1].y += x0.y*w.y; acc[1].z += x0.y*w.z; acc[1].w += x0.y*w.w;
        acc[2].x += x0.z*w.x; acc[2].y += x0.z*w.y; acc[2].z += x0.z*w.z; acc[2].w += x0.z*w.w;
        acc[3].x += x0.w*w.x; acc[3].y += x0.w*w.y; acc[3].z += x0.w*w.z; acc[3].w += x0.w*w.w;
        acc[4].x += x1.x*w.x; acc[4].y += x1.x*w.y; acc[4].z += x1.x*w.z; acc[4].w += x1.x*w.w;
        acc[5].x += x1.y*w.x; acc[5].y += x1.y*w.y; acc[5].z += x1.y*w.z; acc[5].w += x1.y*w.w;
        acc[6].x += x1.z*w.x; acc[6].y += x1.z*w.y; acc[6].z += x1.z*w.z; acc[6].w += x1.z*w.w;
        acc[7].x += x1.w*w.x; acc[7].y += x1.w*w.y; acc[7].z += x1.w*w.z; acc[7].w += x1.w*w.w;
    }
    #pragma unroll
    for (int b = 0; b < 8; ++b)
        *(float4*)&plm[(size_t)(c*8 + b)*VOCAB_ + n0] = acc[b];
}

// ---------------- K5: lm_head combine -> logits ----------------
__global__ __launch_bounds__(256) void k_lm_comb(const float* __restrict__ plm,
                                                 float* __restrict__ out) {
    const int b = blockIdx.y;
    const int n4 = blockIdx.x * 256 + threadIdx.x;
    if (n4 >= VOCAB_/4) return;
    float4 s = make_float4(0.f,0.f,0.f,0.f);
    #pragma unroll
    for (int c = 0; c < KSP_LM; ++c) {
        float4 p = ((const float4*)plm)[(size_t)(c*8 + b)*(VOCAB_/4) + n4];
        s.x += p.x; s.y += p.y; s.z += p.z; s.w += p.w;
    }
    ((float4*)out)[(size_t)b*(VOCAB_/4) + n4] = s;
}

extern "C" void kernel_launch(void* const* d_in, const int* in_sizes, int n_in,
                              void* d_out, int out_size, void* d_ws, size_t ws_size,
                              hipStream_t stream) {
    const int*   tokens    = (const int*)  d_in[0];
    const int*   positions = (const int*)  d_in[1];
    const int*   btab      = (const int*)  d_in[2];
    const float* kc        = (const float*)d_in[3];
    const float* vc        = (const float*)d_in[4];
    const float* embed     = (const float*)d_in[5];
    const float* Wq        = (const float*)d_in[6];
    const float* Wk        = (const float*)d_in[7];
    const float* Wv        = (const float*)d_in[8];
    const float* Wo        = (const float*)d_in[9];
    const float* Wlm       = (const float*)d_in[10];
    float* out = (float*)d_out;
    float* ws  = (float*)d_ws;

    float* pqkv = ws + OFF_PQKV;
    float* pm   = ws + OFF_PM;
    float* pl   = ws + OFF_PL;
    float* pacc = ws + OFF_PACC;
    float* po   = ws + OFF_PO;
    float* plm  = ws + OFF_PLM;

    k_qkv_part<<<dim3(NCOL_QKV/256, KSP_QKV), 256, 0, stream>>>(tokens, embed, Wq, Wk, Wv, pqkv);
    k_attn    <<<dim3(NCHUNK, HKV_, B_), 256, 0, stream>>>(pqkv, kc, vc, positions, btab,
                                                           pm, pl, pacc);
    k_o_part  <<<dim3(HID_/256, KSP_O), 256, 0, stream>>>(pm, pl, pacc, Wo, po);
    k_lm_part <<<dim3((VOCAB_ + 1023)/1024, KSP_LM), 256, 0, stream>>>(tokens, embed, po, Wlm, plm);
    k_lm_comb <<<dim3((VOCAB_/4 + 255)/256, B_), 256, 0, stream>>>(plm, out);
}

// Round 13
// 110.856 us; speedup vs baseline: 1.1154x; 1.0019x over previous
//
#include <hip/hip_runtime.h>
#include <cstdint>
#include <cstddef>

// ---- problem constants ----
constexpr int B_    = 8;
constexpr int HKV_  = 8;
constexpr int G_    = 2;      // query heads per kv head
constexpr int D_    = 128;
constexpr int HID_  = 2048;
constexpr int VOCAB_= 32000;
constexpr int BS_   = 16;
constexpr int MAXB_ = 256;
constexpr int L_    = 4096;

// ---- tiling (CHUNK=64 best; hoisted qkv combine this round) ----
constexpr int KSP_QKV = 32;  constexpr int CK_QKV = HID_ / KSP_QKV;  // 64
constexpr int KSP_O   = 32;                                          // 64 K-rows each
constexpr int KSP_LM  = 16;  constexpr int CK_LM  = HID_ / KSP_LM;   // 128
constexpr int CHUNK   = 64;  constexpr int NCHUNK = L_ / CHUNK;      // 64
constexpr int NCOL_QKV = HID_ + 1024 + 1024;                         // 4096

// ---- workspace layout (floats) ----
constexpr size_t OFF_PQKV = 0;                                         // 32*8*4096
constexpr size_t OFF_QB   = OFF_PQKV + (size_t)KSP_QKV*B_*NCOL_QKV;    // 8*2048 (scaled q)
constexpr size_t OFF_KNV  = OFF_QB   + (size_t)B_*HID_;                // 8*8*256 (kn|vn)
constexpr size_t OFF_PM   = OFF_KNV  + (size_t)B_*HKV_*2*D_;
constexpr size_t OFF_PL   = OFF_PM   + (size_t)B_*HKV_*NCHUNK*G_;
constexpr size_t OFF_PACC = OFF_PL   + (size_t)B_*HKV_*NCHUNK*G_;
constexpr size_t OFF_PO   = OFF_PACC + (size_t)B_*HKV_*NCHUNK*G_*D_;
constexpr size_t OFF_PLM  = OFF_PO   + (size_t)KSP_O*B_*HID_;
// end = OFF_PLM + 16*8*32000 ~= 6.9M floats ~= 28 MB

// ---- nontemporal load helpers ----
// NT on streamed operands (KV cache, Wq/Wk/Wv/Wo) so they don't evict Wlm from
// the 256 MB L3; Wlm uses cached loads (L3-persist across replays — round-6 win).
typedef float f32x4_t __attribute__((ext_vector_type(4)));
__device__ __forceinline__ float4 ntload4(const float* p) {
    f32x4_t v = __builtin_nontemporal_load((const f32x4_t*)p);
    return make_float4(v.x, v.y, v.z, v.w);
}
__device__ __forceinline__ float ntload1(const float* p) {
    return __builtin_nontemporal_load(p);
}

// ---------------- K1: fused q/k/v projection partials ----------------
__global__ __launch_bounds__(256) void k_qkv_part(const int* __restrict__ tokens,
        const float* __restrict__ embed,
        const float* __restrict__ Wq, const float* __restrict__ Wk,
        const float* __restrict__ Wv, float* __restrict__ pout) {
    __shared__ float xs[CK_QKV * 8];           // [kk][b]
    const int c  = blockIdx.y;
    const int k0 = c * CK_QKV;
    const int n  = blockIdx.x * 256 + threadIdx.x;   // 0..4095
    for (int idx = threadIdx.x; idx < CK_QKV*8; idx += 256) {
        int b = idx >> 6, kk = idx & (CK_QKV-1);
        xs[kk*8 + b] = embed[(size_t)tokens[b]*HID_ + k0 + kk];
    }
    const float* Wp; int stride, col;
    if (n < HID_)            { Wp = Wq; stride = HID_; col = n; }
    else if (n < HID_+1024)  { Wp = Wk; stride = 1024; col = n - HID_; }
    else                     { Wp = Wv; stride = 1024; col = n - HID_ - 1024; }
    __syncthreads();
    float acc[8] = {0,0,0,0,0,0,0,0};
    const float* wp = Wp + (size_t)k0 * stride + col;
    #pragma unroll 16
    for (int kk = 0; kk < CK_QKV; ++kk) {
        float w = ntload1(wp); wp += stride;
        float4 x0 = *(const float4*)&xs[kk*8];
        float4 x1 = *(const float4*)&xs[kk*8 + 4];
        acc[0] += x0.x*w; acc[1] += x0.y*w; acc[2] += x0.z*w; acc[3] += x0.w*w;
        acc[4] += x1.x*w; acc[5] += x1.y*w; acc[6] += x1.z*w; acc[7] += x1.w*w;
    }
    float* po = pout + (size_t)c * 8 * NCOL_QKV + n;
    #pragma unroll
    for (int b = 0; b < 8; ++b) po[(size_t)b*NCOL_QKV] = acc[b];
}

// ---------------- K1.5: combine qkv partials once -> qb (scaled), knv ----------------
__global__ __launch_bounds__(256) void k_qkv_comb(const float* __restrict__ pqkv,
        float* __restrict__ qb, float* __restrict__ knv) {
    const int tg = blockIdx.x*256 + threadIdx.x;   // 0..8191
    const float4* pq4 = (const float4*)pqkv;
    const float scale = 0.08838834764831845f;      // 1/sqrt(128)
    if (tg < 4096) {                       // q: b = tg>>9, float4-col = tg&511
        const int b = tg >> 9, c4 = tg & 511;
        float4 s = make_float4(0.f,0.f,0.f,0.f);
        for (int cc = 0; cc < KSP_QKV; ++cc) {
            float4 p = pq4[(size_t)(cc*8 + b)*(NCOL_QKV/4) + c4];
            s.x += p.x; s.y += p.y; s.z += p.z; s.w += p.w;
        }
        s.x*=scale; s.y*=scale; s.z*=scale; s.w*=scale;
        ((float4*)qb)[(size_t)b*512 + c4] = s;
    } else {                               // kn|vn per (b,hkv): 64 float4 each
        const int u2 = tg - 4096;
        const int b = u2 >> 9, r = u2 & 511;
        const int hkv = r >> 6, j = r & 63;
        const size_t cb4 = (j < 32) ? (size_t)(512 + hkv*32 + j)
                                    : (size_t)(768 + hkv*32 + (j - 32));
        float4 s = make_float4(0.f,0.f,0.f,0.f);
        for (int cc = 0; cc < KSP_QKV; ++cc) {
            float4 p = pq4[(size_t)(cc*8 + b)*(NCOL_QKV/4) + cb4];
            s.x += p.x; s.y += p.y; s.z += p.z; s.w += p.w;
        }
        ((float4*)knv)[(size_t)(b*8 + hkv)*64 + j] = s;
    }
}

// ---------------- K2: flash-decode attention (direct qb/knv reads) ----------------
__global__ __launch_bounds__(256) void k_attn(const float* __restrict__ qb,
        const float* __restrict__ knv,
        const float* __restrict__ kc, const float* __restrict__ vc,
        const int* __restrict__ positions, const int* __restrict__ btab,
        float* __restrict__ pm, float* __restrict__ pl, float* __restrict__ pacc) {
    const int ch = blockIdx.x, hkv = blockIdx.y, b = blockIdx.z;
    const int pos = positions[b];
    const int c0  = ch * CHUNK;
    const size_t pbase = (size_t)(b*HKV_ + hkv)*NCHUNK + ch;
    const int t = threadIdx.x;
    if (c0 > pos) {
        if (t < 2) { pm[pbase*2 + t] = -1e30f; pl[pbase*2 + t] = 0.f; }
        pacc[pbase*256 + t] = 0.f;
        return;
    }
    const bool haspos = (pos < c0 + CHUNK);   // c0 <= pos already

    __shared__ int   bts[CHUNK/BS_];
    __shared__ float acc_l[8][256];
    __shared__ float ml_l[8][2][2];

    if (t < CHUNK/BS_) bts[t] = btab[b*MAXB_ + ch*(CHUNK/BS_) + t];
    __syncthreads();

    const int hw = t >> 5, l32 = t & 31;
    const float4* qb4  = (const float4*)qb;
    const float4* knv4 = (const float4*)knv;
    float4 q0 = qb4[(size_t)b*512 + hkv*64 + l32];        // pre-scaled
    float4 q1 = qb4[(size_t)b*512 + hkv*64 + 32 + l32];

    float m0 = -1e30f, m1 = -1e30f, l0 = 0.f, l1 = 0.f;
    float a0[4] = {0,0,0,0}, a1[4] = {0,0,0,0};

    #pragma unroll 8
    for (int i = 0; i < CHUNK/8; ++i) {
        const int lo = i*8 + hw;                 // offset in chunk, uniform per half-wave
        const int l  = c0 + lo;
        const bool valid = (l < pos);            // l==pos handled separately
        size_t row = (size_t)bts[lo >> 4] * BS_ + (lo & (BS_-1));
        size_t off = (row*HKV_ + hkv)*D_ + l32*4;
        float4 kv = ntload4(kc + off);
        float4 vv = ntload4(vc + off);
        float s0 = q0.x*kv.x + q0.y*kv.y + q0.z*kv.z + q0.w*kv.w;
        float s1 = q1.x*kv.x + q1.y*kv.y + q1.z*kv.z + q1.w*kv.w;
        #pragma unroll
        for (int m = 16; m >= 1; m >>= 1) { s0 += __shfl_xor(s0, m); s1 += __shfl_xor(s1, m); }
        if (!valid) { s0 = -1e30f; s1 = -1e30f; }
        float nm0 = fmaxf(m0, s0);
        float cr0 = __expf(m0 - nm0);
        float p0  = valid ? __expf(s0 - nm0) : 0.f;
        m0 = nm0; l0 = l0*cr0 + p0;
        a0[0] = a0[0]*cr0 + p0*vv.x; a0[1] = a0[1]*cr0 + p0*vv.y;
        a0[2] = a0[2]*cr0 + p0*vv.z; a0[3] = a0[3]*cr0 + p0*vv.w;
        float nm1 = fmaxf(m1, s1);
        float cr1 = __expf(m1 - nm1);
        float p1  = valid ? __expf(s1 - nm1) : 0.f;
        m1 = nm1; l1 = l1*cr1 + p1;
        a1[0] = a1[0]*cr1 + p1*vv.x; a1[1] = a1[1]*cr1 + p1*vv.y;
        a1[2] = a1[2]*cr1 + p1*vv.z; a1[3] = a1[3]*cr1 + p1*vv.w;
    }

    // new-token update (cache value at slot is stale; use combined kn/vn)
    if (haspos && hw == 0) {
        float4 kv = knv4[(size_t)(b*8 + hkv)*64 + l32];
        float4 vv = knv4[(size_t)(b*8 + hkv)*64 + 32 + l32];
        float s0 = q0.x*kv.x + q0.y*kv.y + q0.z*kv.z + q0.w*kv.w;
        float s1 = q1.x*kv.x + q1.y*kv.y + q1.z*kv.z + q1.w*kv.w;
        #pragma unroll
        for (int m = 16; m >= 1; m >>= 1) { s0 += __shfl_xor(s0, m); s1 += __shfl_xor(s1, m); }
        float nm0 = fmaxf(m0, s0);
        float cr0 = __expf(m0 - nm0);
        float p0  = __expf(s0 - nm0);
        m0 = nm0; l0 = l0*cr0 + p0;
        a0[0] = a0[0]*cr0 + p0*vv.x; a0[1] = a0[1]*cr0 + p0*vv.y;
        a0[2] = a0[2]*cr0 + p0*vv.z; a0[3] = a0[3]*cr0 + p0*vv.w;
        float nm1 = fmaxf(m1, s1);
        float cr1 = __expf(m1 - nm1);
        float p1  = __expf(s1 - nm1);
        m1 = nm1; l1 = l1*cr1 + p1;
        a1[0] = a1[0]*cr1 + p1*vv.x; a1[1] = a1[1]*cr1 + p1*vv.y;
        a1[2] = a1[2]*cr1 + p1*vv.z; a1[3] = a1[3]*cr1 + p1*vv.w;
    }

    *(float4*)&acc_l[hw][0*D_ + l32*4] = make_float4(a0[0],a0[1],a0[2],a0[3]);
    *(float4*)&acc_l[hw][1*D_ + l32*4] = make_float4(a1[0],a1[1],a1[2],a1[3]);
    if (l32 == 0) {
        ml_l[hw][0][0] = m0; ml_l[hw][0][1] = l0;
        ml_l[hw][1][0] = m1; ml_l[hw][1][1] = l1;
    }
    __syncthreads();

    const int g = t >> 7, d = t & 127;
    float M = -1e30f;
    #pragma unroll
    for (int h = 0; h < 8; ++h) M = fmaxf(M, ml_l[h][g][0]);
    float Ls = 0.f, val = 0.f;
    #pragma unroll
    for (int h = 0; h < 8; ++h) {
        float w = __expf(ml_l[h][g][0] - M);
        Ls  += w * ml_l[h][g][1];
        val += w * acc_l[h][g*D_ + d];
    }
    pacc[pbase*256 + t] = val;
    if (d == 0) { pm[pbase*2 + g] = M; pl[pbase*2 + g] = Ls; }
}

// ---------------- K3: o_proj partials (inline attention combine) ----------------
__global__ __launch_bounds__(256) void k_o_part(const float* __restrict__ pm,
        const float* __restrict__ pl, const float* __restrict__ pacc,
        const float* __restrict__ Wo, float* __restrict__ po) {
    const int cb   = blockIdx.y;            // 0..31
    const int head = cb >> 1;               // query head 0..15
    const int hkv  = head >> 1, g = head & 1;
    const int dhalf = (cb & 1) * 64;        // which 64 dims of the head
    const int t = threadIdx.x;
    const int n = blockIdx.x * 256 + t;     // 0..2047

    __shared__ float pms[8][NCHUNK], pls[8][NCHUNK];   // 2 KB each (NCHUNK=64)
    __shared__ float wch[8][NCHUNK];
    __shared__ float wsum[8];
    __shared__ float xs[64 * 8];            // [kk][b]

    {   // load pm/pl for all (b, ch): 8*64 = 512 entries, 2 per thread
        #pragma unroll
        for (int r = 0; r < 2; ++r) {
            int id = t + r*256;             // 0..511
            int bb = id >> 6, ch = id & 63;
            size_t ix = ((size_t)(bb*HKV_ + hkv)*NCHUNK + ch)*2 + g;
            pms[bb][ch] = pm[ix];
            pls[bb][ch] = pl[ix];
        }
    }
    __syncthreads();
    if (t < 8) {
        float M = -1e30f;
        for (int ch = 0; ch < NCHUNK; ++ch) M = fmaxf(M, pms[t][ch]);
        float Ls = 0.f;
        for (int ch = 0; ch < NCHUNK; ++ch) {
            float w = __expf(pms[t][ch] - M);
            wch[t][ch] = w;
            Ls += w * pls[t][ch];
        }
        wsum[t] = 1.f / Ls;
    }
    __syncthreads();
    if (t < 128) {      // stage attn-out slice [8 b][64 d] via float4
        int bb = t >> 4, j = t & 15;
        float4 a = make_float4(0.f,0.f,0.f,0.f);
        size_t base4 = ((size_t)(bb*HKV_ + hkv)*NCHUNK)*64 + (size_t)(g*128 + dhalf)/4 + j;
        for (int ch = 0; ch < NCHUNK; ++ch) {
            float w = wch[bb][ch];
            float4 p = ((const float4*)pacc)[base4 + (size_t)ch*64];
            a.x += w*p.x; a.y += w*p.y; a.z += w*p.z; a.w += w*p.w;
        }
        float inv = wsum[bb];
        xs[(j*4+0)*8 + bb] = a.x*inv;
        xs[(j*4+1)*8 + bb] = a.y*inv;
        xs[(j*4+2)*8 + bb] = a.z*inv;
        xs[(j*4+3)*8 + bb] = a.w*inv;
    }
    __syncthreads();

    float acc[8] = {0,0,0,0,0,0,0,0};
    const float* wp = Wo + (size_t)(head*D_ + dhalf) * HID_ + n;
    #pragma unroll 16
    for (int kk = 0; kk < 64; ++kk) {
        float w = ntload1(wp); wp += HID_;
        float4 x0 = *(const float4*)&xs[kk*8];
        float4 x1 = *(const float4*)&xs[kk*8 + 4];
        acc[0] += x0.x*w; acc[1] += x0.y*w; acc[2] += x0.z*w; acc[3] += x0.w*w;
        acc[4] += x1.x*w; acc[5] += x1.y*w; acc[6] += x1.z*w; acc[7] += x1.w*w;
    }
    #pragma unroll
    for (int b = 0; b < 8; ++b) po[((size_t)cb*8 + b)*HID_ + n] = acc[b];
}

// ---------------- K4: lm_head partials (inline residual + po combine) ----------------
// Wlm loads CACHED (not NT): Wlm is 256 MB = L3 size and is re-read every
// replay — letting it persist in Infinity Cache is the round-6 win.
__global__ __launch_bounds__(256) void k_lm_part(const int* __restrict__ tokens,
        const float* __restrict__ embed, const float* __restrict__ po,
        const float* __restrict__ Wlm, float* __restrict__ plm) {
    __shared__ float xs[CK_LM * 8];         // [kk][b], 4 KB
    const int c  = blockIdx.y;
    const int k0 = c * CK_LM;
    const int t  = threadIdx.x;
    {   // stage y[b][k0..k0+128) = embed + sum of 32 po partials
        int bb = t >> 5, j = t & 31;        // j: float4 within 128 cols
        size_t col4 = (size_t)(k0 >> 2) + j;
        float4 a = ((const float4*)embed)[(size_t)tokens[bb]*(HID_/4) + col4];
        for (int c2 = 0; c2 < KSP_O; ++c2) {
            float4 p = ((const float4*)po)[(size_t)(c2*8 + bb)*(HID_/4) + col4];
            a.x += p.x; a.y += p.y; a.z += p.z; a.w += p.w;
        }
        xs[(j*4+0)*8 + bb] = a.x;
        xs[(j*4+1)*8 + bb] = a.y;
        xs[(j*4+2)*8 + bb] = a.z;
        xs[(j*4+3)*8 + bb] = a.w;
    }
    __syncthreads();

    const int n0 = blockIdx.x * 1024 + t * 4;
    if (n0 >= VOCAB_) return;
    float4 acc[8];
    #pragma unroll
    for (int b = 0; b < 8; ++b) acc[b] = make_float4(0.f,0.f,0.f,0.f);
    const float* wp = Wlm + (size_t)k0 * VOCAB_ + n0;
    #pragma unroll 8
    for (int kk = 0; kk < CK_LM; ++kk) {
        float4 w = *(const float4*)wp; wp += VOCAB_;   // cached load (L3-persist)
        float4 x0 = *(const float4*)&xs[kk*8];
        float4 x1 = *(const float4*)&xs[kk*8 + 4];
        acc[0].x += x0.x*w.x; acc[0].y += x0.x*w.y; acc[0].z += x0.x*w.z; acc[0].w += x0.x*w.w;
        acc[1].x += x0.y*w.x; acc[1].y += x0.y*w.y; acc[1].z += x0.y*w.z; acc[1].w += x0.y*w.w;
        acc[2].x += x0.z*w.x; acc[2].y += x0.z*w.y; acc[2].z += x0.z*w.z; acc[2].w += x0.z*w.w;
        acc[3].x += x0.w*w.x; acc[3].y += x0.w*w.y; acc[3].z += x0.w*w.z; acc[3].w += x0.w*w.w;
        acc[4].x += x1.x*w.x; acc[4].y += x1.x*w.y; acc[4].z += x1.x*w.z; acc[4].w += x1.x*w.w;
        acc[5].x += x1.y*w.x; acc[5].y += x1.y*w.y; acc[5].z += x1.y*w.z; acc[5].w += x1.y*w.w;
        acc[6].x += x1.z*w.x; acc[6].y += x1.z*w.y; acc[6].z += x1.z*w.z; acc[6].w += x1.z*w.w;
        acc[7].x += x1.w*w.x; acc[7].y += x1.w*w.y; acc[7].z += x1.w*w.z; acc[7].w += x1.w*w.w;
    }
    #pragma unroll
    for (int b = 0; b < 8; ++b)
        *(float4*)&plm[(size_t)(c*8 + b)*VOCAB_ + n0] = acc[b];
}

// ---------------- K5: lm_head combine -> logits ----------------
__global__ __launch_bounds__(256) void k_lm_comb(const float* __restrict__ plm,
                                                 float* __restrict__ out) {
    const int b = blockIdx.y;
    const int n4 = blockIdx.x * 256 + threadIdx.x;
    if (n4 >= VOCAB_/4) return;
    float4 s = make_float4(0.f,0.f,0.f,0.f);
    #pragma unroll
    for (int c = 0; c < KSP_LM; ++c) {
        float4 p = ((const float4*)plm)[(size_t)(c*8 + b)*(VOCAB_/4) + n4];
        s.x += p.x; s.y += p.y; s.z += p.z; s.w += p.w;
    }
    ((float4*)out)[(size_t)b*(VOCAB_/4) + n4] = s;
}

extern "C" void kernel_launch(void* const* d_in, const int* in_sizes, int n_in,
                              void* d_out, int out_size, void* d_ws, size_t ws_size,
                              hipStream_t stream) {
    const int*   tokens    = (const int*)  d_in[0];
    const int*   positions = (const int*)  d_in[1];
    const int*   btab      = (const int*)  d_in[2];
    const float* kc        = (const float*)d_in[3];
    const float* vc        = (const float*)d_in[4];
    const float* embed     = (const float*)d_in[5];
    const float* Wq        = (const float*)d_in[6];
    const float* Wk        = (const float*)d_in[7];
    const float* Wv        = (const float*)d_in[8];
    const float* Wo        = (const float*)d_in[9];
    const float* Wlm       = (const float*)d_in[10];
    float* out = (float*)d_out;
    float* ws  = (float*)d_ws;

    float* pqkv = ws + OFF_PQKV;
    float* qb   = ws + OFF_QB;
    float* knv  = ws + OFF_KNV;
    float* pm   = ws + OFF_PM;
    float* pl   = ws + OFF_PL;
    float* pacc = ws + OFF_PACC;
    float* po   = ws + OFF_PO;
    float* plm  = ws + OFF_PLM;

    k_qkv_part<<<dim3(NCOL_QKV/256, KSP_QKV), 256, 0, stream>>>(tokens, embed, Wq, Wk, Wv, pqkv);
    k_qkv_comb<<<32, 256, 0, stream>>>(pqkv, qb, knv);
    k_attn    <<<dim3(NCHUNK, HKV_, B_), 256, 0, stream>>>(qb, knv, kc, vc, positions, btab,
                                                           pm, pl, pacc);
    k_o_part  <<<dim3(HID_/256, KSP_O), 256, 0, stream>>>(pm, pl, pacc, Wo, po);
    k_lm_part <<<dim3((VOCAB_ + 1023)/1024, KSP_LM), 256, 0, stream>>>(tokens, embed, po, Wlm, plm);
    k_lm_comb <<<dim3((VOCAB_/4 + 255)/256, B_), 256, 0, stream>>>(plm, out);
}